// Round 4
// baseline (360.368 us; speedup 1.0000x reference)
//
#include <hip/hip_runtime.h>

#define D_IN 512
#define D_OUT 256
#define BM 64     // gemm M-tile
#define BN 256    // full D_OUT: A is read from HBM exactly once
#define BK 32
#define NT (D_IN / BK)   // 16 K-tiles

typedef short short8 __attribute__((ext_vector_type(8)));
typedef float floatx4 __attribute__((ext_vector_type(4)));

static __device__ __forceinline__ unsigned short f2bf(float f) {
    unsigned u = __float_as_uint(f);
    u += 0x7FFF + ((u >> 16) & 1);
    return (unsigned short)(u >> 16);
}
static __device__ __forceinline__ float bf2f(unsigned short h) {
    return __uint_as_float((unsigned)h << 16);
}

// ---------------- fused: W convert+transpose + cnt/partials zeroing ----------------
// blocks [0, 256): Wt[n][k] = bf16(W[k][n]);  blocks [256, ...): zero cnt[M]+partials[16]
#define CONV_BLOCKS 256
__global__ __launch_bounds__(512) void convert_and_zero(const float* __restrict__ W,
                                                        unsigned short* __restrict__ Wt,
                                                        int* __restrict__ cnt, int NZ) {
    int b = blockIdx.x;
    if (b < CONV_BLOCKS) {
        int t = b * 512 + threadIdx.x;     // D_IN*D_OUT = 131072 = 256*512
        int n = t >> 9;
        int k = t & 511;
        Wt[t] = f2bf(W[(size_t)k * D_OUT + n]);
    } else {
        int i = (b - CONV_BLOCKS) * 512 + threadIdx.x;
        if (i < NZ) cnt[i] = 0;
    }
}

// ---------------- CSR build: histogram (4 edges/thread) ----------------
__global__ __launch_bounds__(256) void hist_rows(const int* __restrict__ rows,
                                                 int* __restrict__ cnt, int E) {
    int e0 = (blockIdx.x * 256 + threadIdx.x) * 4;
    if (e0 + 3 < E) {
        int4 r = *(const int4*)(rows + e0);
        atomicAdd(&cnt[r.x], 1);
        atomicAdd(&cnt[r.y], 1);
        atomicAdd(&cnt[r.z], 1);
        atomicAdd(&cnt[r.w], 1);
    } else {
        for (int e = e0; e < E; ++e) atomicAdd(&cnt[rows[e]], 1);
    }
}

// ---------------- scan with decoupled lookback (13 blocks, all co-resident) ------
// partials[b] = blockTotal | READY, published atomically; block b polls j<b.
// Produces fully-global exclusive scan in ptr -> add_offsets dispatch eliminated.
#define SCAN_B 4096
#define SCAN_READY (1 << 30)
__global__ __launch_bounds__(1024) void scan_blocks(const int* __restrict__ cnt,
                                                    int* __restrict__ ptr,
                                                    int* __restrict__ partials, int M) {
    __shared__ int wsum[16];
    __shared__ int s_off;
    const int t = threadIdx.x, lane = t & 63, wave = t >> 6;
    const int base = blockIdx.x * SCAN_B + t * 4;
    int4 v = make_int4(0, 0, 0, 0);
    if (base + 3 < M) v = *(const int4*)(cnt + base);
    else {
        if (base + 0 < M) v.x = cnt[base + 0];
        if (base + 1 < M) v.y = cnt[base + 1];
        if (base + 2 < M) v.z = cnt[base + 2];
        if (base + 3 < M) v.w = cnt[base + 3];
    }
    int s = v.x + v.y + v.z + v.w;
    int incl = s;
#pragma unroll
    for (int off = 1; off < 64; off <<= 1) {
        int x = __shfl_up(incl, off, 64);
        if (lane >= off) incl += x;
    }
    if (lane == 63) wsum[wave] = incl;
    __syncthreads();
    if (t == 0) {
        int run = 0;
#pragma unroll
        for (int w = 0; w < 16; ++w) { int x = wsum[w]; wsum[w] = run; run += x; }
        // publish own total, then gather prefix of predecessors
        atomicExch(&partials[blockIdx.x], run | SCAN_READY);
        int off = 0;
        for (int j = 0; j < (int)blockIdx.x; ++j) {
            int pv;
            do { pv = atomicAdd(&partials[j], 0); } while (!(pv & SCAN_READY));
            off += pv & ~SCAN_READY;
        }
        s_off = off;
    }
    __syncthreads();
    int g = s_off + wsum[wave] + (incl - s);
    int e0 = g, e1 = e0 + v.x, e2 = e1 + v.y, e3 = e2 + v.z;
    if (base + 3 < M) *(int4*)(ptr + base) = make_int4(e0, e1, e2, e3);
    else {
        if (base + 0 < M) ptr[base + 0] = e0;
        if (base + 1 < M) ptr[base + 1] = e1;
        if (base + 2 < M) ptr[base + 2] = e2;
        if (base + 3 < M) ptr[base + 3] = e3;
    }
}

// ---------------- fused: GEMM (blocks [0,nGemm)) + edge placement (tail) ---------
// GEMM: S(bf16) = bf16(A) @ bf16(W). BM=64 x BN=256, BK=32, 8 waves, wave tile
// 64x32. k-plane LDS layout [p][row][8] -> 16-lane groups access 16 contiguous
// 16B chunks on write and read: bank-conflict-free (verified round 2).
// DEPTH-2 register prefetch ring (named sets r0/r1, unroll-2 loop): load for
// tile t+2 issued at step t -> ~2 iterations (~600cy) of latency cover.
__global__ __launch_bounds__(512) void gemm_build(
    const float* __restrict__ A, const unsigned short* __restrict__ Wt,
    unsigned short* __restrict__ S, int M, int nGemm,
    const float* __restrict__ vals, const int* __restrict__ rows,
    const int* __restrict__ cols, int* __restrict__ ptr,
    unsigned long long* __restrict__ edges, int E) {
    __shared__ unsigned short As[4 * BM * 8];   // 4 KB
    __shared__ unsigned short Bs[4 * BN * 8];   // 16 KB
    const int bid = blockIdx.x;
    const int tid = threadIdx.x;

    if (bid >= nGemm) {
        // ---- build role (tail): 2048 edges (4 consecutive/thread), destructive ----
        int e0 = (bid - nGemm) * 2048 + tid * 4;
        if (e0 + 3 < E) {
            int4   rr = *(const int4*)(rows + e0);
            int4   cc = *(const int4*)(cols + e0);
            float4 vv = *(const float4*)(vals + e0);
            int p0 = atomicAdd(&ptr[rr.x], 1);
            __builtin_nontemporal_store(
                (unsigned long long)(unsigned)cc.x |
                ((unsigned long long)(unsigned)__float_as_int(vv.x) << 32), edges + p0);
            int p1 = atomicAdd(&ptr[rr.y], 1);
            __builtin_nontemporal_store(
                (unsigned long long)(unsigned)cc.y |
                ((unsigned long long)(unsigned)__float_as_int(vv.y) << 32), edges + p1);
            int p2 = atomicAdd(&ptr[rr.z], 1);
            __builtin_nontemporal_store(
                (unsigned long long)(unsigned)cc.z |
                ((unsigned long long)(unsigned)__float_as_int(vv.z) << 32), edges + p2);
            int p3 = atomicAdd(&ptr[rr.w], 1);
            __builtin_nontemporal_store(
                (unsigned long long)(unsigned)cc.w |
                ((unsigned long long)(unsigned)__float_as_int(vv.w) << 32), edges + p3);
        } else {
            for (int e = e0; e < E; ++e) {
                int pos = atomicAdd(&ptr[rows[e]], 1);
                unsigned long long packed =
                    (unsigned long long)(unsigned)cols[e] |
                    ((unsigned long long)(unsigned)__float_as_int(vals[e]) << 32);
                __builtin_nontemporal_store(packed, edges + pos);
            }
        }
        return;
    }

    // ---- gemm role ----
    const int bm   = bid * BM;
    const int lane = tid & 63;
    const int wave = tid >> 6;
    const int l15  = lane & 15;
    const int quad = lane >> 4;      // 0..3
    const int wn   = wave * 32;      // 8 waves cover 256 cols

    // A staging (threads 0..255): chunk = plane*64 + row (8 elems = 16B LDS, 32B global)
    const bool isA  = tid < 256;
    const int  arow = tid & 63;
    const int  apl  = (tid >> 6) & 3;
    const bool aval = isA && (bm + arow) < M;
    const float* aptr = A + (size_t)(aval ? bm + arow : 0) * D_IN + apl * 8;
    const int awoff = (apl * BM + arow) * 8;

    // B staging (all 512): 2 chunks/thread; chunk ci = p*256 + brow
    const int brow = tid & 255;
    const int bp0  = tid >> 8;                    // 0..1
    const unsigned short* bptr0 = Wt + (size_t)brow * D_IN + bp0 * 8;
    const unsigned short* bptr1 = Wt + (size_t)brow * D_IN + (bp0 + 2) * 8;
    const int bwoff0 = (bp0 * BN + brow) * 8;
    const int bwoff1 = ((bp0 + 2) * BN + brow) * 8;

    // depth-2 prefetch ring: r0 = even tiles, r1 = odd tiles
    float4 a0lo, a0hi, a1lo, a1hi;
    short8 b0r0, b0r1, b1r0, b1r1;
    const float4 fz = make_float4(0.f, 0.f, 0.f, 0.f);
    a0lo = aval ? *(const float4*)(aptr + 0) : fz;
    a0hi = aval ? *(const float4*)(aptr + 4) : fz;
    b0r0 = *(const short8*)(bptr0 + 0);
    b0r1 = *(const short8*)(bptr1 + 0);
    a1lo = aval ? *(const float4*)(aptr + BK) : fz;
    a1hi = aval ? *(const float4*)(aptr + BK + 4) : fz;
    b1r0 = *(const short8*)(bptr0 + BK);
    b1r1 = *(const short8*)(bptr1 + BK);

    floatx4 acc[4][2] = {};

#define GEMM_STEP(T, ALO, AHI, BR0, BR1)                                          \
    {                                                                             \
        if (isA) {                                                                \
            short8 a8;                                                            \
            a8[0] = (short)f2bf(ALO.x); a8[1] = (short)f2bf(ALO.y);               \
            a8[2] = (short)f2bf(ALO.z); a8[3] = (short)f2bf(ALO.w);               \
            a8[4] = (short)f2bf(AHI.x); a8[5] = (short)f2bf(AHI.y);               \
            a8[6] = (short)f2bf(AHI.z); a8[7] = (short)f2bf(AHI.w);               \
            *(short8*)(As + awoff) = a8;                                          \
        }                                                                         \
        *(short8*)(Bs + bwoff0) = BR0;                                            \
        *(short8*)(Bs + bwoff1) = BR1;                                            \
        __syncthreads();                                                          \
        if ((T) + 2 < NT) {                                                       \
            int ko = ((T) + 2) * BK;                                              \
            ALO = aval ? *(const float4*)(aptr + ko) : fz;                        \
            AHI = aval ? *(const float4*)(aptr + ko + 4) : fz;                    \
            BR0 = *(const short8*)(bptr0 + ko);                                   \
            BR1 = *(const short8*)(bptr1 + ko);                                   \
        }                                                                         \
        short8 af[4], bfr[2];                                                     \
        _Pragma("unroll")                                                         \
        for (int i = 0; i < 4; ++i)                                               \
            af[i] = *(const short8*)(As + (quad * BM + i * 16 + l15) * 8);        \
        _Pragma("unroll")                                                         \
        for (int j = 0; j < 2; ++j)                                               \
            bfr[j] = *(const short8*)(Bs + (quad * BN + wn + j * 16 + l15) * 8);  \
        _Pragma("unroll")                                                         \
        for (int i = 0; i < 4; ++i)                                               \
            _Pragma("unroll")                                                     \
            for (int j = 0; j < 2; ++j)                                           \
                acc[i][j] = __builtin_amdgcn_mfma_f32_16x16x32_bf16(              \
                    af[i], bfr[j], acc[i][j], 0, 0, 0);                           \
        __syncthreads();                                                          \
    }

#pragma unroll
    for (int t2 = 0; t2 < NT; t2 += 2) {
        GEMM_STEP(t2,     a0lo, a0hi, b0r0, b0r1);
        GEMM_STEP(t2 + 1, a1lo, a1hi, b1r0, b1r1);
    }
#undef GEMM_STEP

    // epilogue: row = bm+i*16+quad*4+r, col = wn+j*16+l15
#pragma unroll
    for (int i = 0; i < 4; ++i) {
#pragma unroll
        for (int r = 0; r < 4; ++r) {
            int gm = bm + i * 16 + quad * 4 + r;
            if (gm < M) {
#pragma unroll
                for (int j = 0; j < 2; ++j)
                    S[(size_t)gm * D_OUT + wn + j * 16 + l15] = f2bf(acc[i][j][r]);
            }
        }
    }
}

// ---------------- Aggregate: one wave/row, 8-edge unroll, fp32 accum ----------------
// Reads shifted (destructive) CSR: row extent = [row ? ptr[row-1] : 0, ptr[row]).
__global__ __launch_bounds__(256) void spmm_rows(const unsigned short* __restrict__ S,
                                                 const int2* __restrict__ edges,
                                                 const int* __restrict__ ptr,
                                                 const float* __restrict__ bias,
                                                 float* __restrict__ out, int M) {
    const int row = blockIdx.x * 4 + (threadIdx.x >> 6);
    if (row >= M) return;
    const int lane = threadIdx.x & 63;
    float4 a0 = ((const float4*)bias)[lane];
    float4 a1 = make_float4(0.f, 0.f, 0.f, 0.f);
    const int beg = row ? ptr[row - 1] : 0;
    const int end = ptr[row];
    int j = beg;
    for (; j + 7 < end; j += 8) {
        int2 e0 = edges[j + 0], e1 = edges[j + 1], e2 = edges[j + 2], e3 = edges[j + 3];
        int2 e4 = edges[j + 4], e5 = edges[j + 5], e6 = edges[j + 6], e7 = edges[j + 7];
        ushort4 s0 = ((const ushort4*)(S + (size_t)e0.x * D_OUT))[lane];
        ushort4 s1 = ((const ushort4*)(S + (size_t)e1.x * D_OUT))[lane];
        ushort4 s2 = ((const ushort4*)(S + (size_t)e2.x * D_OUT))[lane];
        ushort4 s3 = ((const ushort4*)(S + (size_t)e3.x * D_OUT))[lane];
        ushort4 s4 = ((const ushort4*)(S + (size_t)e4.x * D_OUT))[lane];
        ushort4 s5 = ((const ushort4*)(S + (size_t)e5.x * D_OUT))[lane];
        ushort4 s6 = ((const ushort4*)(S + (size_t)e6.x * D_OUT))[lane];
        ushort4 s7 = ((const ushort4*)(S + (size_t)e7.x * D_OUT))[lane];
        float v0 = __int_as_float(e0.y), v1 = __int_as_float(e1.y);
        float v2 = __int_as_float(e2.y), v3 = __int_as_float(e3.y);
        float v4 = __int_as_float(e4.y), v5 = __int_as_float(e5.y);
        float v6 = __int_as_float(e6.y), v7 = __int_as_float(e7.y);
        a0.x += v0 * bf2f(s0.x) + v2 * bf2f(s2.x) + v4 * bf2f(s4.x) + v6 * bf2f(s6.x);
        a0.y += v0 * bf2f(s0.y) + v2 * bf2f(s2.y) + v4 * bf2f(s4.y) + v6 * bf2f(s6.y);
        a0.z += v0 * bf2f(s0.z) + v2 * bf2f(s2.z) + v4 * bf2f(s4.z) + v6 * bf2f(s6.z);
        a0.w += v0 * bf2f(s0.w) + v2 * bf2f(s2.w) + v4 * bf2f(s4.w) + v6 * bf2f(s6.w);
        a1.x += v1 * bf2f(s1.x) + v3 * bf2f(s3.x) + v5 * bf2f(s5.x) + v7 * bf2f(s7.x);
        a1.y += v1 * bf2f(s1.y) + v3 * bf2f(s3.y) + v5 * bf2f(s5.y) + v7 * bf2f(s7.y);
        a1.z += v1 * bf2f(s1.z) + v3 * bf2f(s3.z) + v5 * bf2f(s5.z) + v7 * bf2f(s7.z);
        a1.w += v1 * bf2f(s1.w) + v3 * bf2f(s3.w) + v5 * bf2f(s5.w) + v7 * bf2f(s7.w);
    }
    for (; j + 3 < end; j += 4) {
        int2 e0 = edges[j], e1 = edges[j + 1], e2 = edges[j + 2], e3 = edges[j + 3];
        ushort4 s0 = ((const ushort4*)(S + (size_t)e0.x * D_OUT))[lane];
        ushort4 s1 = ((const ushort4*)(S + (size_t)e1.x * D_OUT))[lane];
        ushort4 s2 = ((const ushort4*)(S + (size_t)e2.x * D_OUT))[lane];
        ushort4 s3 = ((const ushort4*)(S + (size_t)e3.x * D_OUT))[lane];
        float v0 = __int_as_float(e0.y), v1 = __int_as_float(e1.y);
        float v2 = __int_as_float(e2.y), v3 = __int_as_float(e3.y);
        a0.x += v0 * bf2f(s0.x) + v2 * bf2f(s2.x);
        a0.y += v0 * bf2f(s0.y) + v2 * bf2f(s2.y);
        a0.z += v0 * bf2f(s0.z) + v2 * bf2f(s2.z);
        a0.w += v0 * bf2f(s0.w) + v2 * bf2f(s2.w);
        a1.x += v1 * bf2f(s1.x) + v3 * bf2f(s3.x);
        a1.y += v1 * bf2f(s1.y) + v3 * bf2f(s3.y);
        a1.z += v1 * bf2f(s1.z) + v3 * bf2f(s3.z);
        a1.w += v1 * bf2f(s1.w) + v3 * bf2f(s3.w);
    }
    for (; j < end; ++j) {
        int2 e = edges[j];
        float v = __int_as_float(e.y);
        ushort4 s = ((const ushort4*)(S + (size_t)e.x * D_OUT))[lane];
        a0.x += v * bf2f(s.x);
        a0.y += v * bf2f(s.y);
        a0.z += v * bf2f(s.z);
        a0.w += v * bf2f(s.w);
    }
    a0.x += a1.x; a0.y += a1.y; a0.z += a1.z; a0.w += a1.w;
    // out is never re-read: non-temporal store keeps S resident in caches
    floatx4 res = {a0.x, a0.y, a0.z, a0.w};
    __builtin_nontemporal_store(res, (floatx4*)(out + (size_t)row * D_OUT) + lane);
}

extern "C" void kernel_launch(void* const* d_in, const int* in_sizes, int n_in,
                              void* d_out, int out_size, void* d_ws, size_t ws_size,
                              hipStream_t stream) {
    const float* inputs    = (const float*)d_in[0];
    const float* weights   = (const float*)d_in[1];
    const float* bias      = (const float*)d_in[2];
    const float* edge_vals = (const float*)d_in[3];
    const int*   edge_row  = (const int*)d_in[4];
    const int*   edge_col  = (const int*)d_in[5];
    float* out = (float*)d_out;

    const int M = in_sizes[0] / D_IN;  // 50000
    const int E = in_sizes[3];         // 800000

    // Workspace:
    //   S: M*D_OUT bf16 | Wt: D_OUT*D_IN bf16 | edges: E u64 | ptr: M+1 | cnt: M | partials: 16
    char* ws = (char*)d_ws;
    unsigned short* S  = (unsigned short*)ws;
    unsigned short* Wt = (unsigned short*)(ws + (size_t)M * D_OUT * 2);
    unsigned long long* edges = (unsigned long long*)((char*)Wt + (size_t)D_OUT * D_IN * 2);
    int*  ptr          = (int*)((char*)edges + (size_t)E * 8);
    int*  cnt          = ptr + ((M + 4) & ~3);
    int*  partials     = cnt + M;      // contiguous after cnt -> zeroed together

    // 1) W -> bf16 transposed, fused with cnt+partials zeroing
    int NZ = M + 16;
    convert_and_zero<<<CONV_BLOCKS + (NZ + 511) / 512, 512, 0, stream>>>(weights, Wt, cnt, NZ);

    // 2) CSR histogram + single-dispatch global scan (decoupled lookback)
    hist_rows<<<(E + 1023) / 1024, 256, 0, stream>>>(edge_row, cnt, E);
    scan_blocks<<<(M + SCAN_B - 1) / SCAN_B, 1024, 0, stream>>>(cnt, ptr, partials, M);

    // 3) GEMM (first 782 blocks) + destructive edge placement (tail 391 blocks)
    int nGemm  = (M + BM - 1) / BM;       // 782
    int nBuild = (E + 2047) / 2048;       // 391
    gemm_build<<<nGemm + nBuild, 512, 0, stream>>>(inputs, Wt, S, M, nGemm,
                                                   edge_vals, edge_row, edge_col,
                                                   ptr, edges, E);

    // 4) aggregate (shifted CSR bounds)
    spmm_rows<<<(M + 3) / 4, 256, 0, stream>>>(S, (const int2*)edges, ptr, bias, out, M);
}